// Round 9
// baseline (322.690 us; speedup 1.0000x reference)
//
#include <hip/hip_runtime.h>
#include <math.h>

constexpr int B_  = 32;
constexpr int N_  = 200000;
constexpr int XSZ = 256;
constexpr int PADS = 257;                   // SoA LDS row stride (floats)

// workspace layout (bytes) — total 33,631,232 (identical to proven footprint)
constexpr size_t OFF_PART  = 0;                                    // 256*72*4
constexpr size_t OFF_H     = 73728;                                // 32*8*4
constexpr size_t OFF_R     = 74752;                                // 32*9*4
constexpr size_t OFF_IMG   = 76800;                                // 8 MB
constexpr size_t OFF_TILES = OFF_IMG + (size_t)B_ * XSZ * XSZ * 4; // 16 MB (512 tiles)
constexpr size_t OFF_W5T   = OFF_TILES + (size_t)512 * 8192 * 4;   // 6.4 MB
// post-scatter overlays (tiles/w5t dead after k_merge):
constexpr size_t OFF_TMP   = OFF_TILES;                            // 8 MB blur tmp
constexpr size_t OFF_FC    = OFF_TILES + (size_t)B_ * XSZ * XSZ * 4; // 16.8 MB float2

__device__ __forceinline__ int rev8(int x) { return (int)(__brev((unsigned)x) >> 24); }

// ---------------- T reduction: T[j,i,k] = sum_n coords[n,j] * W1[3n+i,k] ----------------
__global__ __launch_bounds__(256) void k_reduceT(const float* __restrict__ coords,
                                                 const float* __restrict__ W1,
                                                 float* __restrict__ partial) {
  float acc[72];
  #pragma unroll
  for (int t = 0; t < 72; ++t) acc[t] = 0.f;
  int idx = blockIdx.x * 256 + threadIdx.x;
  for (int n = idx; n < N_; n += 256 * 256) {
    float c0 = coords[n * 3 + 0], c1 = coords[n * 3 + 1], c2 = coords[n * 3 + 2];
    const float4* w4 = reinterpret_cast<const float4*>(W1 + (size_t)n * 24);
    #pragma unroll
    for (int i = 0; i < 3; ++i) {
      float4 wa = w4[i * 2 + 0], wb = w4[i * 2 + 1];
      float wv[8] = {wa.x, wa.y, wa.z, wa.w, wb.x, wb.y, wb.z, wb.w};
      #pragma unroll
      for (int k = 0; k < 8; ++k) {
        acc[i * 8 + k]      += c0 * wv[k];
        acc[24 + i * 8 + k] += c1 * wv[k];
        acc[48 + i * 8 + k] += c2 * wv[k];
      }
    }
  }
  #pragma unroll
  for (int t = 0; t < 72; ++t) {
    float v = acc[t];
    for (int off = 32; off > 0; off >>= 1) v += __shfl_down(v, off, 64);
    acc[t] = v;
  }
  __shared__ float sred[4][72];
  int lane = threadIdx.x & 63, wv_ = threadIdx.x >> 6;
  if (lane == 0) {
    #pragma unroll
    for (int t = 0; t < 72; ++t) sred[wv_][t] = acc[t];
  }
  __syncthreads();
  if (threadIdx.x < 72) {
    int t = threadIdx.x;
    partial[blockIdx.x * 72 + t] = sred[0][t] + sred[1][t] + sred[2][t] + sred[3][t];
  }
}

// ---------------- per-batch: finalize T, rotation matrices, MLP head ----------------
__global__ __launch_bounds__(128) void k_batch(const float* __restrict__ partial,
                                               const float* __restrict__ rows,
                                               const float* __restrict__ b1,
                                               const float* __restrict__ Wh,
                                               const float* __restrict__ bh,
                                               float* __restrict__ hbuf,
                                               float* __restrict__ Rbuf) {
  __shared__ float T[72];
  int tid = threadIdx.x;
  if (tid < 72) {
    double s = 0.0;
    for (int i = 0; i < 256; ++i) s += (double)partial[i * 72 + tid];
    T[tid] = (float)s;
  }
  __syncthreads();
  if (tid < B_) {
    int b = tid;
    float al = rows[b * 3 + 0], be = rows[b * 3 + 1], ga = rows[b * 3 + 2];
    float sa, ca, sb, cb, sg, cg;
    sincosf(al, &sa, &ca); sincosf(be, &sb, &cb); sincosf(ga, &sg, &cg);
    float R[3][3];
    R[0][0] = ca * cb * cg - sa * sg; R[0][1] = -ca * cb * sg - sa * cg; R[0][2] = ca * sb;
    R[1][0] = sa * cb * cg + ca * sg; R[1][1] = -sa * cb * sg + ca * cg; R[1][2] = sa * sb;
    R[2][0] = -sb * cg;               R[2][1] = sb * sg;                 R[2][2] = cb;
    float h[8];
    #pragma unroll
    for (int k = 0; k < 8; ++k) {
      float z = b1[k];
      #pragma unroll
      for (int i = 0; i < 3; ++i)
        #pragma unroll
        for (int j = 0; j < 3; ++j)
          z += R[i][j] * T[(j * 3 + i) * 8 + k];
      h[k] = sinf(30.f * z);
    }
    for (int l = 0; l < 3; ++l) {
      float nh[8];
      #pragma unroll
      for (int k2 = 0; k2 < 8; ++k2) {
        float z = bh[l * 8 + k2];
        #pragma unroll
        for (int k1 = 0; k1 < 8; ++k1) z += h[k1] * Wh[l * 64 + k1 * 8 + k2];
        nh[k2] = sinf(z);
      }
      #pragma unroll
      for (int k = 0; k < 8; ++k) h[k] = nh[k];
    }
    #pragma unroll
    for (int k = 0; k < 8; ++k) hbuf[b * 8 + k] = h[k];
    #pragma unroll
    for (int i = 0; i < 3; ++i)
      #pragma unroll
      for (int j = 0; j < 3; ++j) Rbuf[b * 9 + i * 3 + j] = R[i][j];
  }
}

// ---------------- W5 transpose: W5T[n][k] = W5[k][n] ----------------
__global__ __launch_bounds__(256) void k_w5t(const float* __restrict__ W5, float* __restrict__ w5t) {
  int n = blockIdx.x * 256 + threadIdx.x;
  if (n >= N_) return;
  float v[8];
  #pragma unroll
  for (int k = 0; k < 8; ++k) v[k] = W5[(size_t)k * N_ + n];
  float4* dst = reinterpret_cast<float4*>(w5t + (size_t)n * 8);
  dst[0] = make_float4(v[0], v[1], v[2], v[3]);
  dst[1] = make_float4(v[4], v[5], v[6], v[7]);
}

// ---------------- direct scatter v3: wave-compaction; block = (image, band, half) ----------------
__global__ __launch_bounds__(1024) void k_direct3(const float* __restrict__ coords,
                                                  const float* __restrict__ w5t,
                                                  const float* __restrict__ b5,
                                                  const float* __restrict__ hbuf,
                                                  const float* __restrict__ Rbuf,
                                                  const float* __restrict__ shifts,
                                                  float* __restrict__ tiles) {
  __shared__ float tile[32 * XSZ];        // 32 KB
  __shared__ unsigned sstack[16 * 128];   // 8 KB: per-wave stacks of accepted n
  __shared__ float sp[16];
  int tid = threadIdx.x;
  int bid = blockIdx.x;
  int b = bid >> 4;
  int band = (bid >> 1) & 7;
  int half = bid & 1;
  int r0 = band << 5;
  if (tid < 6)       sp[tid] = Rbuf[b * 9 + tid] * 100.f;
  else if (tid < 8)  sp[tid] = 128.f - shifts[b * 2 + (tid - 6)];
  else if (tid < 16) sp[tid] = hbuf[b * 8 + (tid - 8)];
  for (int i = tid; i < 32 * XSZ; i += 1024) tile[i] = 0.f;
  __syncthreads();
  const float A0 = sp[0], A1 = sp[1], A2 = sp[2];
  const float A3 = sp[3], A4 = sp[4], A5 = sp[5];
  const float bx = sp[6], by = sp[7];
  const float h0 = sp[8], h1 = sp[9], h2 = sp[10], h3 = sp[11];
  const float h4 = sp[12], h5 = sp[13], h6 = sp[14], h7 = sp[15];
  const float ylo = (float)(r0 - 1), yhi = (float)(r0 + 32);
  const int lane = tid & 63;
  const unsigned woff = (unsigned)(tid >> 6) << 7;   // wave stack base (128 entries)
  const int nbeg = half * (N_ / 2), nend = nbeg + (N_ / 2);

  auto process = [&](unsigned nn) {
    float c0 = coords[nn * 3], c1 = coords[nn * 3 + 1], c2 = coords[nn * 3 + 2];
    float px = fmaf(A0, c0, fmaf(A1, c1, fmaf(A2, c2, bx)));
    float py = fmaf(A3, c0, fmaf(A4, c1, fmaf(A5, c2, by)));
    const float4* w = reinterpret_cast<const float4*>(w5t + (size_t)nn * 8);
    float4 wa = w[0], wb = w[1];
    float delta = b5[nn];
    delta = fmaf(h0, wa.x, delta); delta = fmaf(h1, wa.y, delta);
    delta = fmaf(h2, wa.z, delta); delta = fmaf(h3, wa.w, delta);
    delta = fmaf(h4, wb.x, delta); delta = fmaf(h5, wb.y, delta);
    delta = fmaf(h6, wb.z, delta); delta = fmaf(h7, wb.w, delta);
    float x0f = floorf(px), y0f = floorf(py);
    float fx = px - x0f, fy = py - y0f;
    int x0 = (int)x0f;
    int r = (int)y0f - r0;              // in [-1, 31]
    float wy0 = (1.f - fy) * delta, wy1 = fy * delta;
    bool xl = (x0 >= 0), xr = (x0 <= 254);
    if (r >= 0) {
      int c0i = r * XSZ + x0;
      if (xl) atomicAdd(&tile[c0i], (1.f - fx) * wy0);
      if (xr) atomicAdd(&tile[c0i + 1], fx * wy0);
    }
    if (r < 31) {
      int c1i = (r + 1) * XSZ + x0;
      if (xl) atomicAdd(&tile[c1i], (1.f - fx) * wy1);
      if (xr) atomicAdd(&tile[c1i + 1], fx * wy1);
    }
  };

  unsigned cnt = 0;                      // wave-uniform stack depth
  const int iters = (N_ / 2 + 1023) / 1024;   // 98, uniform for all waves
  for (int it = 0; it < iters; ++it) {
    int n = nbeg + it * 1024 + tid;
    bool pred = false;
    if (n < nend) {
      float c0 = coords[n * 3], c1 = coords[n * 3 + 1], c2 = coords[n * 3 + 2];
      float px = fmaf(A0, c0, fmaf(A1, c1, fmaf(A2, c2, bx)));
      float py = fmaf(A3, c0, fmaf(A4, c1, fmaf(A5, c2, by)));
      pred = (py >= ylo) && (py < yhi) && (px >= -1.f) && (px < 256.f);
    }
    unsigned long long m = __ballot(pred);
    unsigned pos = __builtin_amdgcn_mbcnt_hi((unsigned)(m >> 32),
                   __builtin_amdgcn_mbcnt_lo((unsigned)m, 0u));
    if (pred) sstack[woff + cnt + pos] = (unsigned)n;
    cnt += (unsigned)__popcll(m);
    if (cnt >= 64) {                     // uniform branch; pop top 64 (LIFO, adds commute)
      cnt -= 64;
      unsigned nn = sstack[woff + cnt + lane];
      process(nn);
    }
  }
  if (lane < (int)cnt) {                 // drain remainder, masked
    unsigned nn = sstack[woff + lane];
    process(nn);
  }
  __syncthreads();
  float* dst = tiles + (size_t)bid * 8192;
  for (int i = tid; i < 8192; i += 1024) dst[i] = tile[i];
}

// ---------------- merge the two half-tiles into img ----------------
__global__ __launch_bounds__(256) void k_merge(const float* __restrict__ tiles,
                                               float* __restrict__ img) {
  int i = blockIdx.x * 256 + threadIdx.x;     // [0, 2M)
  int b = i >> 16;
  int y = (i >> 8) & 255;
  int x = i & 255;
  int band = y >> 5, r = y & 31;
  size_t t0 = ((size_t)((b << 4) + (band << 1))) * 8192 + r * 256 + x;
  img[i] = tiles[t0] + tiles[t0 + 8192];
}

// ---------------- separable Gaussian blur (zero-padded SAME) ----------------
__device__ __forceinline__ float bwv(int i) {
  const float bw[7] = {0.004433048f, 0.054005582f, 0.242036226f, 0.399050280f,
                       0.242036226f, 0.054005582f, 0.004433048f};
  return bw[i];
}

__global__ __launch_bounds__(256) void k_blurV(const float* __restrict__ in, float* __restrict__ out) {
  int i = blockIdx.x * 256 + threadIdx.x;
  int x = i & 255;
  int y = (i >> 8) & 255;
  const float* p = in + (i & ~65535);
  float s = 0.f;
  #pragma unroll
  for (int d = -3; d <= 3; ++d) {
    int yy = y + d;
    if ((unsigned)yy < XSZ) s += bwv(d + 3) * p[(yy << 8) + x];
  }
  out[i] = s;
}

__global__ __launch_bounds__(256) void k_blurH(const float* __restrict__ in, float* __restrict__ out) {
  int i = blockIdx.x * 256 + threadIdx.x;
  int x = i & 255;
  float s = 0.f;
  #pragma unroll
  for (int d = -3; d <= 3; ++d) {
    int xx = x + d;
    if ((unsigned)xx < XSZ) s += bwv(d + 3) * in[i + d];
  }
  out[i] = s;
}

// ---------------- FFT helpers: 256-pt, SoA in LDS, stride PADS ----------------
__device__ __forceinline__ void fft_dif_fwd(float* re, float* im, const float2* tw, int P, int tid) {
  for (int s = 7; s >= 0; --s) {
    __syncthreads();
    int half = 1 << s;
    for (int q = tid; q < (P << 7); q += 256) {
      int p = q >> 7, k = q & 127;
      int j = k & (half - 1);
      int i0 = ((k >> s) << (s + 1)) | j;
      int i1 = i0 + half;
      float* rp = re + p * PADS; float* ip = im + p * PADS;
      float ar = rp[i0], ai = ip[i0], br = rp[i1], bi = ip[i1];
      rp[i0] = ar + br; ip[i0] = ai + bi;
      float tr = ar - br, ti = ai - bi;
      float2 w = tw[j << (7 - s)];
      rp[i1] = tr * w.x - ti * w.y;
      ip[i1] = tr * w.y + ti * w.x;
    }
  }
  __syncthreads();
}

__device__ __forceinline__ void fft_dit_inv(float* re, float* im, const float2* tw, int P, int tid) {
  for (int s = 0; s <= 7; ++s) {
    __syncthreads();
    int half = 1 << s;
    for (int q = tid; q < (P << 7); q += 256) {
      int p = q >> 7, k = q & 127;
      int j = k & (half - 1);
      int i0 = ((k >> s) << (s + 1)) | j;
      int i1 = i0 + half;
      float* rp = re + p * PADS; float* ip = im + p * PADS;
      float2 w = tw[j << (7 - s)];               // conj -> (w.x, -w.y)
      float br = rp[i1], bi = ip[i1];
      float tr = br * w.x + bi * w.y;
      float ti = bi * w.x - br * w.y;
      float ar = rp[i0], ai = ip[i0];
      rp[i0] = ar + tr; ip[i0] = ai + ti;
      rp[i1] = ar - tr; ip[i1] = ai - ti;
    }
  }
  __syncthreads();
}

__device__ __forceinline__ void tw_init(float2* tw, int tid) {
  for (int k = tid; k < 128; k += 256) {
    float s_, c_;
    sincosf(-6.2831853071795864769f * (float)k / 256.0f, &s_, &c_);
    tw[k] = make_float2(c_, s_);
  }
}

// F1: row FFT (over x), DIF, store transposed: Fc[b][i][y] holds kx=rev8(i)
__global__ __launch_bounds__(256) void k_fft1(const float* __restrict__ img, float2* __restrict__ Fc) {
  __shared__ float re[16 * PADS], im[16 * PADS];
  __shared__ float2 tw[128];
  int tid = threadIdx.x;
  int b = blockIdx.x >> 4;
  int y0 = (blockIdx.x & 15) << 4;
  tw_init(tw, tid);
  const float* src = img + (size_t)b * 65536 + (size_t)y0 * 256;
  for (int q = tid; q < 4096; q += 256) {
    int j = q >> 8, x = q & 255;
    re[j * PADS + x] = src[j * 256 + x];
    im[j * PADS + x] = 0.f;
  }
  fft_dif_fwd(re, im, tw, 16, tid);
  float2* dst = Fc + (size_t)b * 65536;
  for (int q = tid; q < 4096; q += 256) {
    int j = q & 15, i = q >> 4;
    dst[(size_t)i * 256 + y0 + j] = make_float2(re[j * PADS + i], im[j * PADS + i]);
  }
}

// F2: column FFT (over y) DIF fwd, * ctf_ext, DIT inverse; in-place on Fc rows
__global__ __launch_bounds__(256) void k_fft2(float2* __restrict__ Fc, const float* __restrict__ ctf) {
  __shared__ float re[4 * PADS], im[4 * PADS];
  __shared__ float2 tw[128];
  int tid = threadIdx.x;
  int b = blockIdx.x >> 6;
  int r0 = (blockIdx.x & 63) << 2;
  tw_init(tw, tid);
  float2* base = Fc + (size_t)b * 65536 + (size_t)r0 * 256;
  for (int q = tid; q < 1024; q += 256) {
    int p = q >> 8, y = q & 255;
    float2 v = base[p * 256 + y];
    re[p * PADS + y] = v.x; im[p * PADS + y] = v.y;
  }
  fft_dif_fwd(re, im, tw, 4, tid);
  for (int q = tid; q < 1024; q += 256) {
    int p = q >> 8, iy = q & 255;
    int kx = rev8(r0 + p), ky = rev8(iy);
    float c;
    if (kx <= 128) c = ctf[((size_t)b * 256 + ky) * 129 + kx];
    else           c = ctf[((size_t)b * 256 + ((256 - ky) & 255)) * 129 + (256 - kx)];
    re[p * PADS + iy] *= c; im[p * PADS + iy] *= c;
  }
  fft_dit_inv(re, im, tw, 4, tid);
  for (int q = tid; q < 1024; q += 256) {
    int p = q >> 8, y = q & 255;
    base[p * 256 + y] = make_float2(re[p * PADS + y], im[p * PADS + y]);
  }
}

// F3: inverse row FFT (over kx). Rows of Fc are already bitrev-ordered in kx -> DIT direct.
__global__ __launch_bounds__(256) void k_fft3(const float2* __restrict__ Fc, float* __restrict__ out) {
  __shared__ float re[16 * PADS], im[16 * PADS];
  __shared__ float2 tw[128];
  int tid = threadIdx.x;
  int b = blockIdx.x >> 4;
  int y0 = (blockIdx.x & 15) << 4;
  tw_init(tw, tid);
  const float2* src = Fc + (size_t)b * 65536;
  for (int q = tid; q < 4096; q += 256) {
    int j = q & 15, r = q >> 4;
    float2 v = src[(size_t)r * 256 + y0 + j];
    re[j * PADS + r] = v.x; im[j * PADS + r] = v.y;
  }
  fft_dit_inv(re, im, tw, 16, tid);
  float* dst = out + (size_t)b * 65536 + (size_t)y0 * 256;
  for (int q = tid; q < 4096; q += 256) {
    int j = q >> 8, x = q & 255;
    dst[j * 256 + x] = re[j * PADS + x] * (1.f / 65536.f);
  }
}

extern "C" void kernel_launch(void* const* d_in, const int* in_sizes, int n_in,
                              void* d_out, int out_size, void* d_ws, size_t ws_size,
                              hipStream_t stream) {
  const float* rows   = (const float*)d_in[0];
  const float* shifts = (const float*)d_in[1];
  const float* coords = (const float*)d_in[2];
  const float* W1     = (const float*)d_in[3];
  const float* b1     = (const float*)d_in[4];
  const float* Wh     = (const float*)d_in[5];
  const float* bh     = (const float*)d_in[6];
  const float* W5     = (const float*)d_in[7];
  const float* b5     = (const float*)d_in[8];
  const float* ctf    = (const float*)d_in[9];
  float* out = (float*)d_out;
  char* ws = (char*)d_ws;

  float*    partial = (float*)(ws + OFF_PART);
  float*    hbuf    = (float*)(ws + OFF_H);
  float*    Rbuf    = (float*)(ws + OFF_R);
  float*    img     = (float*)(ws + OFF_IMG);
  float*    tiles   = (float*)(ws + OFF_TILES);
  float*    w5t     = (float*)(ws + OFF_W5T);
  float*    tmp     = (float*)(ws + OFF_TMP);
  float2*   Fc      = (float2*)(ws + OFF_FC);

  k_reduceT<<<256, 256, 0, stream>>>(coords, W1, partial);
  k_batch<<<1, 128, 0, stream>>>(partial, rows, b1, Wh, bh, hbuf, Rbuf);
  k_w5t<<<(N_ + 255) / 256, 256, 0, stream>>>(W5, w5t);
  k_direct3<<<512, 1024, 0, stream>>>(coords, w5t, b5, hbuf, Rbuf, shifts, tiles);
  k_merge<<<B_ * XSZ * XSZ / 256, 256, 0, stream>>>(tiles, img);
  k_blurV<<<B_ * XSZ * XSZ / 256, 256, 0, stream>>>(img, tmp);
  k_blurH<<<B_ * XSZ * XSZ / 256, 256, 0, stream>>>(tmp, img);
  k_fft1<<<B_ * 16, 256, 0, stream>>>(img, Fc);
  k_fft2<<<B_ * 64, 256, 0, stream>>>(Fc, ctf);
  k_fft3<<<B_ * 16, 256, 0, stream>>>(Fc, out);
}